// Round 5
// baseline (292.526 us; speedup 1.0000x reference)
//
#include <hip/hip_runtime.h>
#include <hip/hip_bf16.h>

// LSTMP cell: B=16384, I=512, H=512, K_gates = 1024, 4H = 2048.
// d_in: x[B,I] h_prev[B,H] c_prev[B,H] W[2048,1024] b[2048] gamma[512] beta[512] Wp[512,512]
// d_out: [ out (B*H f32) | cell (B*H f32) ]
//   out slot doubles as A_bf16 [16384][1024] scratch until K3 overwrites it.
// ws: [ s/o bf16 (B*H shorts, 16MB) | W_bf16 (2048*1024, 4MB) | Wp_bf16 (512*512, 0.5MB) ]
//
// R4 post-mortem: K1 (128^2 tile, stage->vmcnt(0)drain->compute->barrier) = 88us
// = m97-structure ceiling. R5: K1 ported to 256^2 / 8-wave / dbuf-128KB with
// COUNTED vmcnt(8) (T3+T4): loads for tile t+1 stay in flight across tile t's
// whole compute; stage into a buffer only after the all-waves-done barrier.

typedef __attribute__((ext_vector_type(4))) float f32x4;
typedef __attribute__((ext_vector_type(8))) short bf16x8;
typedef __attribute__((ext_vector_type(4))) short bf16x4;

#define NB 16384
#define NH 512

__device__ __forceinline__ short f2bf(float f) {
    union { float f; unsigned u; } v; v.f = f;
    unsigned r = v.u + 0x7FFFu + ((v.u >> 16) & 1u);   // RNE
    return (short)(r >> 16);
}
__device__ __forceinline__ float bf2f(short s) {
    union { unsigned u; float f; } v; v.u = ((unsigned)(unsigned short)s) << 16;
    return v.f;
}
__device__ __forceinline__ float sigmoidf_(float x) { return 1.0f / (1.0f + __expf(-x)); }
__device__ __forceinline__ float tanhf_(float x) { return 1.0f - 2.0f / (__expf(2.0f * x) + 1.0f); }

__device__ __forceinline__ void gld16(const void* g, void* l) {
    __builtin_amdgcn_global_load_lds(
        (const __attribute__((address_space(1))) void*)g,
        (__attribute__((address_space(3))) void*)l, 16, 0, 0);
}

// ---------------------------------------------------------------------------
// K0: fused conversion -- A_bf16 = bf16([x|h]), W_bf16 = bf16(W), Wp_bf16 = bf16(Wp)
// ---------------------------------------------------------------------------
__global__ __launch_bounds__(256, 8)
void k_convert(const float* __restrict__ x, const float* __restrict__ h,
               const float* __restrict__ W, const float* __restrict__ Wp,
               short* __restrict__ Abf, short* __restrict__ Wbf,
               short* __restrict__ Wpbf)
{
    const long long nA  = (long long)NB * 256;          // 4,194,304 chunks of 4 f32
    const long long nW  = (long long)2048 * 1024 / 4;   //   524,288
    const long long nWp = (long long)512 * 512 / 4;     //    65,536
    long long i = (long long)blockIdx.x * 256 + threadIdx.x;
    const long long stride = (long long)gridDim.x * 256;
    for (; i < nA + nW + nWp; i += stride) {
        const float* src; short* dst;
        if (i < nA) {
            const int r  = (int)(i >> 8);
            const int c4 = (int)(i & 255);
            src = (c4 < 128) ? (x + (size_t)r * 512 + c4 * 4)
                             : (h + (size_t)r * 512 + (c4 - 128) * 4);
            dst = Abf + i * 4;
        } else if (i < nA + nW) {
            const long long j = i - nA;
            src = W + j * 4; dst = Wbf + j * 4;
        } else {
            const long long j = i - nA - nW;
            src = Wp + j * 4; dst = Wpbf + j * 4;
        }
        f32x4 v = *(const f32x4*)src;
        bf16x4 o;
#pragma unroll
        for (int j = 0; j < 4; ++j) o[j] = f2bf(v[j]);
        *(bf16x4*)dst = o;
    }
}

// ---------------------------------------------------------------------------
// K1: gates GEMM, 256x256 tile, 8 waves, dbuf LDS 128KB, counted vmcnt(8).
// grid (64, 8): x = M-tile (256 rows), y = h-tile (64 h-cols x 4 gates = 256 N).
// Waves 2(M) x 4(N); wave owns 128x64. Fragment n == gate n:
//   virtual col v = wc*64 + n*16 + c  ->  gate = n, h = h0 + wc*16 + c
// Schedule per K-tile t (buf = t&1):
//   COMPUTE(buf): 4 quadrants {8 ds_read_b128, setprio(1), 16 MFMA, setprio(0)}
//                 (no intra-tile barriers -> compiler interleaves q+1 reads
//                  under q's MFMAs)
//   lgkmcnt(0); sched_barrier; s_barrier          // all waves done reading buf
//   STAGE(t+2 -> buf)                              // 8 gld16/thread
//   s_waitcnt vmcnt(8)                             // drain tile t+1 ONLY
//   s_barrier                                      // t+1 visible to all
// ---------------------------------------------------------------------------
__global__ __launch_bounds__(512, 2)
void k_gates_cell(const short* __restrict__ Abf, const short* __restrict__ Wbf,
                  const float* __restrict__ c_prev, const float* __restrict__ bvec,
                  float* __restrict__ cell_raw, short* __restrict__ o_ws)
{
    __shared__ __align__(16) short As[2][256 * 64];   // 64KB
    __shared__ __align__(16) short Bs[2][256 * 64];   // 64KB

    const int tid  = threadIdx.x;      // 0..511
    const int lane = tid & 63;
    const int w    = tid >> 6;         // 0..7
    const int wr = w >> 2, wc = w & 3;
    const int row0 = blockIdx.x * 256;
    const int h0   = blockIdx.y * 64;

    const f32x4 zero = {0.f, 0.f, 0.f, 0.f};
    f32x4 acc[8][4];
#pragma unroll
    for (int m = 0; m < 8; ++m)
#pragma unroll
        for (int n = 0; n < 4; ++n) acc[m][n] = zero;

    // Staging map: chunk ci = j*512 + tid; LDS row = ci>>3 = j*64 + (tid>>3);
    // phys k-chunk = tid&7. Read swizzle is byt ^= (row&7)<<4, so the source
    // k-chunk pre-swizzles: (tid&7) ^ (row&7), row&7 = (tid>>3)&7.
    const int srcK8 = ((tid & 7) ^ ((tid >> 3) & 7)) * 8;   // element offset
    int aOff[4], bOff[4], ldsB[4];
#pragma unroll
    for (int j = 0; j < 4; ++j) {
        const int row = j * 64 + (tid >> 3);                 // 0..255
        aOff[j] = (row0 + row) * 1024 + srcK8;
        const int wrow = ((row >> 4) & 3) * 512 + h0 + (row >> 6) * 16 + (row & 15);
        bOff[j] = wrow * 1024 + srcK8;
        ldsB[j] = (j * 512 + w * 64) * 8;                    // wave-uniform base
    }

#define STAGE(tile, buf) do {                                          \
        const int kb_ = (tile) * 64;                                   \
        _Pragma("unroll")                                              \
        for (int j_ = 0; j_ < 4; ++j_) {                               \
            gld16(Abf + aOff[j_] + kb_, &As[(buf)][ldsB[j_]]);         \
            gld16(Wbf + bOff[j_] + kb_, &Bs[(buf)][ldsB[j_]]);         \
        }                                                              \
    } while (0)

#define COMPUTE(buf) do {                                              \
        _Pragma("unroll")                                              \
        for (int q_ = 0; q_ < 4; ++q_) {                               \
            const int g_ = q_ >> 1, kk_ = (q_ & 1) * 32;               \
            bf16x8 af[4], bfr[4];                                      \
            _Pragma("unroll")                                          \
            for (int mi_ = 0; mi_ < 4; ++mi_) {                        \
                const int row_ = wr * 128 + (g_ * 4 + mi_) * 16 + (lane & 15); \
                int byt_ = row_ * 128 + (kk_ + (lane >> 4) * 8) * 2;   \
                byt_ ^= (row_ & 7) << 4;                               \
                af[mi_] = *(const bf16x8*)((const char*)As[(buf)] + byt_); \
            }                                                          \
            _Pragma("unroll")                                          \
            for (int n_ = 0; n_ < 4; ++n_) {                           \
                const int row_ = wc * 64 + n_ * 16 + (lane & 15);      \
                int byt_ = row_ * 128 + (kk_ + (lane >> 4) * 8) * 2;   \
                byt_ ^= (row_ & 7) << 4;                               \
                bfr[n_] = *(const bf16x8*)((const char*)Bs[(buf)] + byt_); \
            }                                                          \
            __builtin_amdgcn_s_setprio(1);                             \
            _Pragma("unroll")                                          \
            for (int mi_ = 0; mi_ < 4; ++mi_)                          \
                _Pragma("unroll")                                      \
                for (int n_ = 0; n_ < 4; ++n_)                         \
                    acc[g_ * 4 + mi_][n_] = __builtin_amdgcn_mfma_f32_16x16x32_bf16( \
                        af[mi_], bfr[n_], acc[g_ * 4 + mi_][n_], 0, 0, 0); \
            __builtin_amdgcn_s_setprio(0);                             \
        }                                                              \
    } while (0)

    // prologue: tiles 0,1 in flight; wait for tile 0 (keep tile 1 flying)
    STAGE(0, 0);
    STAGE(1, 1);
    asm volatile("s_waitcnt vmcnt(8)" ::: "memory");
    __builtin_amdgcn_s_barrier();

#pragma unroll 1
    for (int t = 0; t < 16; t += 2) {
        COMPUTE(0);                                    // tile t (buf0)
        asm volatile("s_waitcnt lgkmcnt(0)" ::: "memory");
        __builtin_amdgcn_sched_barrier(0);
        __builtin_amdgcn_s_barrier();                  // all waves done with buf0
        if (t + 2 < 16) {
            STAGE(t + 2, 0);
            asm volatile("s_waitcnt vmcnt(8)" ::: "memory");  // drain tile t+1
        } else {
            asm volatile("s_waitcnt vmcnt(0)" ::: "memory");
        }
        __builtin_amdgcn_s_barrier();                  // tile t+1 visible

        COMPUTE(1);                                    // tile t+1 (buf1)
        asm volatile("s_waitcnt lgkmcnt(0)" ::: "memory");
        __builtin_amdgcn_sched_barrier(0);
        __builtin_amdgcn_s_barrier();                  // all waves done with buf1
        if (t + 3 < 16) {
            STAGE(t + 3, 1);
            asm volatile("s_waitcnt vmcnt(8)" ::: "memory");  // drain tile t+2
        } else {
            asm volatile("s_waitcnt vmcnt(0)" ::: "memory");
        }
        __builtin_amdgcn_s_barrier();                  // tile t+2 visible
    }
#undef STAGE
#undef COMPUTE

    // epilogue: thread owns all 4 gates of (row, hcol) for 32 rows
    const int hcol = h0 + wc * 16 + (lane & 15);
    float bias[4];
#pragma unroll
    for (int n = 0; n < 4; ++n) bias[n] = bvec[n * 512 + hcol];
#pragma unroll
    for (int mi = 0; mi < 8; ++mi) {
        const int rbase = row0 + wr * 128 + mi * 16 + ((lane >> 4) * 4);
#pragma unroll
        for (int q = 0; q < 4; ++q) {
            const size_t idx = (size_t)(rbase + q) * 512 + hcol;
            const float iv = acc[mi][0][q] + bias[0];
            const float fv = acc[mi][1][q] + bias[1];
            const float gv = acc[mi][2][q] + bias[2];
            const float ov = acc[mi][3][q] + bias[3];
            const float c = c_prev[idx];
            cell_raw[idx] = sigmoidf_(fv) * c + sigmoidf_(iv) * tanhf_(gv);
            o_ws[idx] = f2bf(sigmoidf_(ov));
        }
    }
}

// ---------------------------------------------------------------------------
// K2: per-row LayerNorm (in place) + s = sigma(o)*tanh(cell)  (in place in s_io)
// grid: 4096 x 256 (4 waves/block, 1 row each)
// ---------------------------------------------------------------------------
__global__ __launch_bounds__(256)
void k_layernorm(const float* __restrict__ gamma, const float* __restrict__ beta,
                 float* __restrict__ cell, short* __restrict__ s_io)
{
    const int r = blockIdx.x * 4 + (threadIdx.x >> 6);
    const int lane = threadIdx.x & 63;
    float* row = cell + (size_t)r * 512;
    f32x4 v0 = *(const f32x4*)(row + lane * 8);
    f32x4 v1 = *(const f32x4*)(row + lane * 8 + 4);
    float s1 = 0.f, s2 = 0.f;
#pragma unroll
    for (int j = 0; j < 4; ++j) {
        s1 += v0[j] + v1[j];
        s2 += v0[j] * v0[j] + v1[j] * v1[j];
    }
#pragma unroll
    for (int off = 32; off > 0; off >>= 1) {
        s1 += __shfl_xor(s1, off);
        s2 += __shfl_xor(s2, off);
    }
    const float mu  = s1 * (1.f / 512.f);
    const float var = s2 * (1.f / 512.f) - mu * mu;
    const float rs  = rsqrtf(var + 1e-5f);
    const f32x4 g0 = *(const f32x4*)(gamma + lane * 8);
    const f32x4 g1 = *(const f32x4*)(gamma + lane * 8 + 4);
    const f32x4 b0 = *(const f32x4*)(beta + lane * 8);
    const f32x4 b1 = *(const f32x4*)(beta + lane * 8 + 4);
    const bf16x8 o8 = *(const bf16x8*)(s_io + (size_t)r * 512 + lane * 8);
    f32x4 c0, c1; bf16x8 s8;
#pragma unroll
    for (int j = 0; j < 4; ++j) {
        c0[j] = (v0[j] - mu) * rs * g0[j] + b0[j];
        c1[j] = (v1[j] - mu) * rs * g1[j] + b1[j];
    }
#pragma unroll
    for (int j = 0; j < 4; ++j) {
        s8[j]     = f2bf(bf2f(o8[j])     * tanhf_(c0[j]));
        s8[j + 4] = f2bf(bf2f(o8[j + 4]) * tanhf_(c1[j]));
    }
    *(f32x4*)(row + lane * 8)     = c0;
    *(f32x4*)(row + lane * 8 + 4) = c1;
    *(bf16x8*)(s_io + (size_t)r * 512 + lane * 8) = s8;
}

// ---------------------------------------------------------------------------
// K3: out = s @ Wp^T  (M=16384, N=512, K=512), bf16, gload_lds, single-buffer
// grid (128, 4)   [proven R4 structure]
// ---------------------------------------------------------------------------
__global__ __launch_bounds__(256, 4)
void k_proj(const short* __restrict__ s_ws, const short* __restrict__ Wpbf,
            float* __restrict__ out)
{
    __shared__ __align__(16) short As[128 * 64];
    __shared__ __align__(16) short Bs[128 * 64];
    const int tid = threadIdx.x;
    const int lane = tid & 63;
    const int wid = tid >> 6;
    const int wr = wid >> 1, wc = wid & 1;
    const int row0 = blockIdx.x * 128;
    const int col0 = blockIdx.y * 128;

    const f32x4 zero = {0.f, 0.f, 0.f, 0.f};
    f32x4 acc[4][4];
#pragma unroll
    for (int m = 0; m < 4; ++m)
#pragma unroll
        for (int n = 0; n < 4; ++n) acc[m][n] = zero;

    const int k8 = ((lane & 7) ^ (lane >> 3)) * 8;
    int aOff[4], bOff[4];
#pragma unroll
    for (int j = 0; j < 4; ++j) {
        const int row = (wid * 4 + j) * 8 + (lane >> 3);
        aOff[j] = (row0 + row) * 512 + k8;
        bOff[j] = (col0 + row) * 512 + k8;
    }

    for (int kt = 0; kt < 8; ++kt) {
        const int kbase = kt * 64;
#pragma unroll
        for (int j = 0; j < 4; ++j) {
            gld16(s_ws + aOff[j] + kbase, As + (wid * 4 + j) * 512);
            gld16(Wpbf + bOff[j] + kbase, Bs + (wid * 4 + j) * 512);
        }
        __syncthreads();
#pragma unroll
        for (int kk = 0; kk < 64; kk += 32) {
            bf16x8 af[4], bfr[4];
#pragma unroll
            for (int m = 0; m < 4; ++m) {
                const int row = wr * 64 + m * 16 + (lane & 15);
                int byt = row * 128 + (kk + (lane >> 4) * 8) * 2;
                byt ^= (row & 7) << 4;
                af[m] = *(const bf16x8*)((const char*)As + byt);
            }
#pragma unroll
            for (int n = 0; n < 4; ++n) {
                const int row = wc * 64 + n * 16 + (lane & 15);
                int byt = row * 128 + (kk + (lane >> 4) * 8) * 2;
                byt ^= (row & 7) << 4;
                bfr[n] = *(const bf16x8*)((const char*)Bs + byt);
            }
#pragma unroll
            for (int m = 0; m < 4; ++m)
#pragma unroll
                for (int n = 0; n < 4; ++n)
                    acc[m][n] = __builtin_amdgcn_mfma_f32_16x16x32_bf16(af[m], bfr[n], acc[m][n], 0, 0, 0);
        }
        __syncthreads();
    }

#pragma unroll
    for (int m = 0; m < 4; ++m) {
        const int grow = row0 + wr * 64 + m * 16 + ((lane >> 4) * 4);
#pragma unroll
        for (int n = 0; n < 4; ++n) {
            const int gcol = col0 + wc * 64 + n * 16 + (lane & 15);
#pragma unroll
            for (int q = 0; q < 4; ++q)
                out[(size_t)(grow + q) * 512 + gcol] = acc[m][n][q];
        }
    }
}

extern "C" void kernel_launch(void* const* d_in, const int* in_sizes, int n_in,
                              void* d_out, int out_size, void* d_ws, size_t ws_size,
                              hipStream_t stream) {
    (void)in_sizes; (void)n_in; (void)out_size; (void)ws_size;
    const float* x      = (const float*)d_in[0];
    const float* h_prev = (const float*)d_in[1];
    const float* c_prev = (const float*)d_in[2];
    const float* W      = (const float*)d_in[3];
    const float* bvec   = (const float*)d_in[4];
    const float* gamma  = (const float*)d_in[5];
    const float* beta   = (const float*)d_in[6];
    const float* Wp     = (const float*)d_in[7];

    float* out  = (float*)d_out;                       // [B*H] f32 (final)
    float* cell = out + (size_t)NB * NH;               // [B*H] f32
    short* Abf  = (short*)d_out;                       // [B][1024] bf16 (dies before K3)
    short* s_io = (short*)d_ws;                        // [B*H] bf16: o, then s in place
    short* Wbf  = s_io + (size_t)NB * NH;              // [2048*1024] bf16
    short* Wpbf = Wbf + (size_t)2048 * 1024;           // [512*512] bf16

    k_convert<<<2048, 256, 0, stream>>>(x, h_prev, W, Wp, Abf, Wbf, Wpbf);
    dim3 g1(NB / 256, 2048 / 256);
    k_gates_cell<<<g1, 512, 0, stream>>>(Abf, Wbf, c_prev, bvec, cell, s_io);
    k_layernorm<<<NB / 4, 256, 0, stream>>>(gamma, beta, cell, s_io);
    dim3 g3(NB / 128, NH / 128);
    k_proj<<<g3, 256, 0, stream>>>(s_io, Wpbf, out);
}